// Round 2
// baseline (2582.881 us; speedup 1.0000x reference)
//
#include <hip/hip_runtime.h>
#include <math.h>

#define B_SZ 4096
#define D_SZ 1024
#define N_SZ 16384
#define K_TOP 32

// ---------------- encode GEMM: h_pre = (x - b_dec) @ W_enc^T + b_enc ----------------
#define BM 128
#define BN 128
#define BK 32

__global__ __launch_bounds__(256) void encode_gemm(
    const float* __restrict__ x, const float* __restrict__ Wenc,
    const float* __restrict__ benc, const float* __restrict__ bdec,
    float* __restrict__ hpre)
{
    __shared__ float As[BK][BM + 4];
    __shared__ float Bs[BK][BN + 4];
    const int tid = threadIdx.x;
    const int tx = tid & 15, ty = tid >> 4;
    const int m0 = blockIdx.y * BM;
    const int n0 = blockIdx.x * BN;

    float acc[8][8];
    #pragma unroll
    for (int i = 0; i < 8; ++i)
        #pragma unroll
        for (int j = 0; j < 8; ++j) acc[i][j] = 0.f;

    for (int k0 = 0; k0 < D_SZ; k0 += BK) {
        #pragma unroll
        for (int q = 0; q < 4; ++q) {
            int v = tid + q * 256;       // float4 id in [0,1024)
            int row = v >> 3;            // 0..127
            int c4  = v & 7;             // 0..7
            float4 a  = *reinterpret_cast<const float4*>(&x[(size_t)(m0 + row) * D_SZ + k0 + c4 * 4]);
            float4 bd = *reinterpret_cast<const float4*>(&bdec[k0 + c4 * 4]);
            As[c4 * 4 + 0][row] = a.x - bd.x;
            As[c4 * 4 + 1][row] = a.y - bd.y;
            As[c4 * 4 + 2][row] = a.z - bd.z;
            As[c4 * 4 + 3][row] = a.w - bd.w;
            float4 b = *reinterpret_cast<const float4*>(&Wenc[(size_t)(n0 + row) * D_SZ + k0 + c4 * 4]);
            Bs[c4 * 4 + 0][row] = b.x;
            Bs[c4 * 4 + 1][row] = b.y;
            Bs[c4 * 4 + 2][row] = b.z;
            Bs[c4 * 4 + 3][row] = b.w;
        }
        __syncthreads();
        #pragma unroll
        for (int kk = 0; kk < BK; ++kk) {
            float4 a0 = *reinterpret_cast<const float4*>(&As[kk][ty * 8]);
            float4 a1 = *reinterpret_cast<const float4*>(&As[kk][ty * 8 + 4]);
            float4 b0 = *reinterpret_cast<const float4*>(&Bs[kk][tx * 8]);
            float4 b1 = *reinterpret_cast<const float4*>(&Bs[kk][tx * 8 + 4]);
            float av[8] = {a0.x, a0.y, a0.z, a0.w, a1.x, a1.y, a1.z, a1.w};
            float bv[8] = {b0.x, b0.y, b0.z, b0.w, b1.x, b1.y, b1.z, b1.w};
            #pragma unroll
            for (int i = 0; i < 8; ++i)
                #pragma unroll
                for (int j = 0; j < 8; ++j)
                    acc[i][j] = fmaf(av[i], bv[j], acc[i][j]);
        }
        __syncthreads();
    }
    #pragma unroll
    for (int i = 0; i < 8; ++i) {
        int row = m0 + ty * 8 + i;
        #pragma unroll
        for (int j4 = 0; j4 < 2; ++j4) {
            int col = n0 + tx * 8 + j4 * 4;
            float4 be = *reinterpret_cast<const float4*>(&benc[col]);
            float4 o;
            o.x = acc[i][j4 * 4 + 0] + be.x;
            o.y = acc[i][j4 * 4 + 1] + be.y;
            o.z = acc[i][j4 * 4 + 2] + be.z;
            o.w = acc[i][j4 * 4 + 3] + be.w;
            *reinterpret_cast<float4*>(&hpre[(size_t)row * N_SZ + col]) = o;
        }
    }
}

// ---------------- per-row top-32 (row held in registers; 32 argmax passes) ----------------
// Element mapping: thread tid owns r[j], j = q*4+e  ->  global idx g = q*1024 + tid*4 + e.
// Ascending j is ascending g within a thread, so strict '>' keeps lowest index on ties,
// matching numpy/jax stable top-k tie-breaking.
__global__ __launch_bounds__(256) void topk_kernel(
    const float* __restrict__ hpre, float* __restrict__ hsparse)
{
    __shared__ float wval[4];
    __shared__ int   wgid[4];
    __shared__ float selV[K_TOP];
    __shared__ int   selI[K_TOP];

    const int tid  = threadIdx.x;
    const int lane = tid & 63;
    const int wid  = tid >> 6;
    const size_t row = blockIdx.x;
    const float* src = hpre + row * (size_t)N_SZ;

    float r[64];
    #pragma unroll
    for (int q = 0; q < 16; ++q) {
        float4 v = *reinterpret_cast<const float4*>(&src[(size_t)(tid + q * 256) * 4]);
        r[q * 4 + 0] = v.x; r[q * 4 + 1] = v.y; r[q * 4 + 2] = v.z; r[q * 4 + 3] = v.w;
    }
    unsigned long long mask = 0ull;  // bit j set => r[j] already selected

    for (int it = 0; it < K_TOP; ++it) {
        float best = -INFINITY;
        int   bj   = 0;
        #pragma unroll
        for (int j = 0; j < 64; ++j) {
            bool avail = ((mask >> j) & 1ull) == 0ull;
            if (avail && r[j] > best) { best = r[j]; bj = j; }
        }
        int bg = (bj >> 2) * 1024 + tid * 4 + (bj & 3);
        // wave reduce (64 lanes), prefer higher val then lower index
        #pragma unroll
        for (int off = 32; off > 0; off >>= 1) {
            float ov = __shfl_down(best, off);
            int   og = __shfl_down(bg, off);
            if (ov > best || (ov == best && og < bg)) { best = ov; bg = og; }
        }
        if (lane == 0) { wval[wid] = best; wgid[wid] = bg; }
        __syncthreads();
        float fv = wval[0]; int fg = wgid[0];
        #pragma unroll
        for (int w = 1; w < 4; ++w) {
            float ov = wval[w]; int og = wgid[w];
            if (ov > fv || (ov == fv && og < fg)) { fv = ov; fg = og; }
        }
        // owner marks its element as consumed
        int owner = (fg >> 2) & 255;
        if (tid == owner) {
            int j = ((fg >> 10) << 2) | (fg & 3);
            mask |= (1ull << j);
        }
        if (tid == 0) { selV[it] = fv; selI[it] = fg; }
        __syncthreads();
    }
    if (tid < K_TOP) {
        hsparse[row * (size_t)N_SZ + selI[tid]] = selV[tid];
    }
}

// ---------------- W_dec transpose: (D x N) -> (N x D) ----------------
__global__ __launch_bounds__(256) void transpose_wdec(
    const float* __restrict__ Wdec, float* __restrict__ WdecT)
{
    __shared__ float tile[32][33];
    const int x0 = blockIdx.x * 32;   // along N
    const int y0 = blockIdx.y * 32;   // along D
    const int tx = threadIdx.x & 31;
    const int ty = threadIdx.x >> 5;  // 0..7
    #pragma unroll
    for (int rr = 0; rr < 4; ++rr) {
        int y = ty + rr * 8;
        tile[y][tx] = Wdec[(size_t)(y0 + y) * N_SZ + x0 + tx];
    }
    __syncthreads();
    #pragma unroll
    for (int rr = 0; rr < 4; ++rr) {
        int y = ty + rr * 8;
        WdecT[(size_t)(x0 + y) * D_SZ + y0 + tx] = tile[tx][y];
    }
}

// ---------------- sparse decode: x_hat = h_sparse @ W_dec^T + b_dec ----------------
// W element for (feature idx, dim d) at W[idx*idxStride + d*dStride]
__global__ __launch_bounds__(256) void decode_kernel(
    const float* __restrict__ hsparse, const float* __restrict__ W,
    const float* __restrict__ bdec, float* __restrict__ xhat,
    long idxStride, long dStride)
{
    __shared__ int   cnt;
    __shared__ int   sidx[64];
    __shared__ float sval[64];
    const int tid = threadIdx.x;
    const size_t row = blockIdx.x;
    if (tid == 0) cnt = 0;
    __syncthreads();

    const float* src = hsparse + row * (size_t)N_SZ;
    #pragma unroll
    for (int q = 0; q < 16; ++q) {
        int v4 = (tid + q * 256) * 4;
        float4 v = *reinterpret_cast<const float4*>(&src[v4]);
        if (v.x != 0.f) { int p = atomicAdd(&cnt, 1); sidx[p] = v4 + 0; sval[p] = v.x; }
        if (v.y != 0.f) { int p = atomicAdd(&cnt, 1); sidx[p] = v4 + 1; sval[p] = v.y; }
        if (v.z != 0.f) { int p = atomicAdd(&cnt, 1); sidx[p] = v4 + 2; sval[p] = v.z; }
        if (v.w != 0.f) { int p = atomicAdd(&cnt, 1); sidx[p] = v4 + 3; sval[p] = v.w; }
    }
    __syncthreads();
    const int c = cnt;

    float acc[4];
    #pragma unroll
    for (int q = 0; q < 4; ++q) acc[q] = bdec[tid + q * 256];
    for (int j = 0; j < c; ++j) {
        const float* base = W + (size_t)sidx[j] * idxStride;
        const float  v = sval[j];
        #pragma unroll
        for (int q = 0; q < 4; ++q)
            acc[q] = fmaf(v, base[(size_t)(tid + q * 256) * dStride], acc[q]);
    }
    #pragma unroll
    for (int q = 0; q < 4; ++q)
        xhat[row * (size_t)D_SZ + tid + q * 256] = acc[q];
}

extern "C" void kernel_launch(void* const* d_in, const int* in_sizes, int n_in,
                              void* d_out, int out_size, void* d_ws, size_t ws_size,
                              hipStream_t stream)
{
    const float* x    = (const float*)d_in[0];
    const float* Wenc = (const float*)d_in[1];
    const float* benc = (const float*)d_in[2];
    const float* Wdec = (const float*)d_in[3];
    const float* bdec = (const float*)d_in[4];

    float* xhat    = (float*)d_out;
    float* hsparse = xhat + (size_t)B_SZ * D_SZ;
    float* hpre    = hsparse + (size_t)B_SZ * N_SZ;

    // h_sparse must be zeroed every call (harness poisons d_out with 0xAA)
    hipMemsetAsync(hsparse, 0, (size_t)B_SZ * N_SZ * sizeof(float), stream);

    dim3 g1(N_SZ / BN, B_SZ / BM);
    encode_gemm<<<g1, 256, 0, stream>>>(x, Wenc, benc, bdec, hpre);

    topk_kernel<<<B_SZ, 256, 0, stream>>>(hpre, hsparse);

    const size_t wt_bytes = (size_t)D_SZ * N_SZ * sizeof(float);
    if (ws_size >= wt_bytes) {
        float* WdecT = (float*)d_ws;
        transpose_wdec<<<dim3(N_SZ / 32, D_SZ / 32), 256, 0, stream>>>(Wdec, WdecT);
        decode_kernel<<<B_SZ, 256, 0, stream>>>(hsparse, WdecT, bdec, xhat,
                                                (long)D_SZ, 1L);
    } else {
        // fallback: strided column access into original W_dec
        decode_kernel<<<B_SZ, 256, 0, stream>>>(hsparse, Wdec, bdec, xhat,
                                                1L, (long)N_SZ);
    }
}